// Round 10
// baseline (127.617 us; speedup 1.0000x reference)
//
#include <hip/hip_runtime.h>

#define HH 512
#define WW 512
#define EPSF 1e-7f
#define DTF 0.05f
#define RS1 2      // rows per wave, pass 1 (256 strips/image -> 8192 waves, 2048 blocks)
#define RSF 8      // output rows per wave, pass 2
#define PANW 256   // panel width, pass 2 (4 cols/lane)

// native clang vector for __builtin_nontemporal_store (HIP float4 class is rejected)
typedef float vfloat4 __attribute__((ext_vector_type(4)));

// lane-to-lane pull via LDS-pipe permute (pass 1 only)
__device__ __forceinline__ float bperm(int addr, float v) {
    return __int_as_float(__builtin_amdgcn_ds_bpermute(addr, __float_as_int(v)));
}

// ---------------- Pass 1: per-wave strip max of e4 -> partial[] (NO atomics) ----------------
// Round-5 evidence: same-address device atomicMax serializes (~11.5 ns each). Plain
// parallel stores + folded reduce in pass 2 is the fast path. RS1=2 doubles the grid:
// VGPR=40 kernel was grid-capped at 4 blocks/CU; 2048 blocks -> 8/CU for latency hiding.
struct R10 { float v[10]; };
struct Raw10 { float4 a, b; };

__device__ __forceinline__ void issue_row10(const float* __restrict__ base, int row,
                                            int lane, Raw10& r) {
    if ((unsigned)row < (unsigned)HH) {               // wave-uniform branch
        const float4* p = (const float4*)(base + (size_t)row * WW + 8 * lane);
        r.a = p[0]; r.b = p[1];
    } else {
        r.a = make_float4(0.f, 0.f, 0.f, 0.f);
        r.b = make_float4(0.f, 0.f, 0.f, 0.f);
    }
}

__device__ __forceinline__ void finish_row10(const Raw10& q, int bpu, int bpd,
                                             bool lo, bool hi, R10& r) {
    r.v[1] = q.a.x; r.v[2] = q.a.y; r.v[3] = q.a.z; r.v[4] = q.a.w;
    r.v[5] = q.b.x; r.v[6] = q.b.y; r.v[7] = q.b.z; r.v[8] = q.b.w;
    float l = bperm(bpu, r.v[8]);
    float h = bperm(bpd, r.v[1]);
    r.v[0] = lo ? 0.f : l;
    r.v[9] = hi ? 0.f : h;
}

__global__ __launch_bounds__(256, 4)
void max_e4_kernel(const float* __restrict__ img, float* __restrict__ partial) {
    const int wid  = blockIdx.x * 4 + (threadIdx.x >> 6);
    const int lane = threadIdx.x & 63;
    const int rs = wid & 255;                // 256 strips of RS1 rows
    const int b  = wid >> 8;
    const int i0 = rs * RS1;
    const float* __restrict__ IM = img + (size_t)b * (HH * WW);
    const bool lo = (lane == 0), hi = (lane == 63);
    const int bpu = ((lane + 63) & 63) << 2, bpd = ((lane + 1) & 63) << 2;

    Raw10 rA, rB;
    issue_row10(IM, i0 - 1, lane, rA);
    issue_row10(IM, i0,     lane, rB);
    R10 A, B, C;
    finish_row10(rA, bpu, bpd, lo, hi, A);
    issue_row10(IM, i0 + 1, lane, rA);
    finish_row10(rB, bpu, bpd, lo, hi, B);
    issue_row10(IM, i0 + 2, lane, rB);
    float m = 0.f;
    #pragma unroll
    for (int k = 0; k < RS1; ++k) {          // row i0+k, uses raw row i0+k+1
        if (k & 1) finish_row10(rB, bpu, bpd, lo, hi, C);
        else       finish_row10(rA, bpu, bpd, lo, hi, C);
        #pragma unroll
        for (int j = 1; j <= 8; ++j) {
            float ex = (A.v[j-1] - A.v[j+1]) + 2.f * (B.v[j-1] - B.v[j+1]) + (C.v[j-1] - C.v[j+1]);
            float ey = (A.v[j-1] - C.v[j-1]) + 2.f * (A.v[j] - C.v[j]) + (A.v[j+1] - C.v[j+1]);
            float s2 = ex * ex + ey * ey;
            m = fmaxf(m, s2 * s2);
        }
        A = B; B = C;
    }
    for (int off = 32; off > 0; off >>= 1)
        m = fmaxf(m, __shfl_down(m, off, 64));
    if (lane == 0) partial[wid] = m;         // 8192 partials, all written every launch
}

// ---------------- Pass 2: bperm-free, 8-wide self-sufficient lane windows ----------------
// Each lane owns output cols g..g+3 and loads cols g-2..g+5 as TWO 8B-aligned float4s
// (4 VMEM/iter, down from 6). Edge lanes use a clamped base + select remap (verified
// col-by-col for g=0 and g=508). e/px computed at 6 cols g-1..g+4 in-lane: halo values
// bitwise-identical to the neighbor lane's center computation. No ds_bpermute.
struct Raw8 { float4 a, b; };
struct W8 { float w[8]; };   // w[j] = col g-2+j (0 outside image)

__device__ __forceinline__ void issue8(const float* __restrict__ base, int row,
                                       int g, bool okL, bool okR, Raw8& r) {
    if ((unsigned)row < (unsigned)HH) {               // wave-uniform branch
        const float* rp = base + (size_t)row * WW;
        r.a = *(const float4*)(rp + (okL ? g - 2 : 0));       // cols g-2..g+1 (clamped)
        r.b = *(const float4*)(rp + (okR ? g + 2 : WW - 4));  // cols g+2..g+5 (clamped)
    } else {
        r.a = make_float4(0.f, 0.f, 0.f, 0.f);
        r.b = make_float4(0.f, 0.f, 0.f, 0.f);
    }
}

__device__ __forceinline__ void finish8(const Raw8& q, bool okL, bool okR, W8& r) {
    // interior: a=g-2..g+1, b=g+2..g+5.  g==0: a=0..3, b=2..5.  g==508: a=506..509, b=508..511.
    r.w[0] = okL ? q.a.x : 0.f;
    r.w[1] = okL ? q.a.y : 0.f;
    r.w[2] = okL ? q.a.z : q.a.x;
    r.w[3] = okL ? q.a.w : q.a.y;
    r.w[4] = okR ? q.b.x : q.b.z;
    r.w[5] = okR ? q.b.y : q.b.w;
    r.w[6] = okR ? q.b.z : 0.f;
    r.w[7] = okR ? q.b.w : 0.f;
}

// (256,2): 256-VGPR cap. Round-1 evidence: never cap at 128 ((256,4)) -> allocator
// collapse + scratch spills. Round-6 evidence: VGPR=92 means the scheduler SANK the
// prefetch loads (collapsed depth-2) -> sched_barrier(0) after each issue block pins them.
__global__ __launch_bounds__(256, 2)
void fused_ff(const float* __restrict__ u, const float* __restrict__ img,
              const float* __restrict__ pa, const float* __restrict__ pb,
              const float* __restrict__ pg, const float* __restrict__ partial,
              float* __restrict__ out) {
    // folded reduce_max: every block redundantly reduces the 8192 LLC-hot partials
    __shared__ float sred[4];
    {
        float v = 0.f;
        #pragma unroll
        for (int k = 0; k < 32; ++k)
            v = fmaxf(v, partial[threadIdx.x + 256 * k]);
        for (int off = 32; off > 0; off >>= 1)
            v = fmaxf(v, __shfl_down(v, off, 64));
        if ((threadIdx.x & 63) == 0) sred[threadIdx.x >> 6] = v;
    }
    __syncthreads();
    const float M = fmaxf(fmaxf(sred[0], sred[1]), fmaxf(sred[2], sred[3]));

    const int wid  = blockIdx.x * 4 + (threadIdx.x >> 6);   // [0,4096)
    const int lane = threadIdx.x & 63;
    const int p  = wid & 1;                  // panel
    const int rs = (wid >> 1) & 63;          // 64 strips of RSF rows
    const int b  = wid >> 7;
    const int o0 = rs * RSF;
    const int g  = p * PANW + 4 * lane;      // lane's first output col
    const size_t base = (size_t)b * (HH * WW);
    const float* __restrict__ U  = u + base;
    const float* __restrict__ IM = img + base;
    float* __restrict__ O = out + base;
    const bool okL = (g >= 2);               // cols g-2,g-1 inside image
    const bool okR = (g + 5 < WW);           // cols g+4,g+5 inside image
    const bool ezL = (g == 0);               // e/px col g-1 is conv-pad zero
    const bool ezR = (g + 4 >= WW);          // e/px col g+4 is conv-pad zero

    const float dta = DTF * pa[0];
    const float dtb = 20.f * DTF * pb[0];
    const float dtg = DTF * pg[0];

    // rolling state: img rows o,o+1 (8-wide); u rows o-1(center),o,o+1 ; e/px/py history
    W8 I0 = {}, I1 = {}, R1 = {}, R2 = {};
    float R0[4] = {}, E1c[4] = {}, E2[6] = {}, PX2[6] = {};
    float PY1c[4] = {}, PY2c[4] = {};

    if (o0 >= 2) {   // wave-uniform preload of rows o0-2, o0-1 (issue all, then finish)
        Raw8 qa, qb, qc, qd;
        issue8(IM, o0 - 2, g, okL, okR, qa);
        issue8(U,  o0 - 2, g, okL, okR, qb);
        issue8(IM, o0 - 1, g, okL, okR, qc);
        issue8(U,  o0 - 1, g, okL, okR, qd);
        finish8(qa, okL, okR, I0);
        finish8(qb, okL, okR, R1);
        finish8(qc, okL, okR, I1);
        finish8(qd, okL, okR, R2);
    }

    // depth-2 prefetch ring: slot A = row o0+kk (even kk), slot B (odd kk)
    Raw8 pAi, pAu, pBi, pBu;
    issue8(IM, o0,     g, okL, okR, pAi);
    issue8(U,  o0,     g, okL, okR, pAu);
    issue8(IM, o0 + 1, g, okL, okR, pBi);
    issue8(U,  o0 + 1, g, okL, okR, pBu);

    #pragma unroll
    for (int kk = 0; kk < RSF + 2; ++kk) {
        const int o = o0 - 2 + kk;           // uses raw row o+2 = o0+kk
        W8 C, W;
        if (kk & 1) {
            finish8(pBi, okL, okR, C);
            finish8(pBu, okL, okR, W);
            if (kk < RSF) {                  // compile-time (kk is unrolled)
                issue8(IM, o0 + kk + 2, g, okL, okR, pBi);
                issue8(U,  o0 + kk + 2, g, okL, okR, pBu);
            }
        } else {
            finish8(pAi, okL, okR, C);
            finish8(pAu, okL, okR, W);
            if (kk < RSF) {
                issue8(IM, o0 + kk + 2, g, okL, okR, pAi);
                issue8(U,  o0 + kk + 2, g, okL, okR, pAu);
            }
        }
        // Pin the prefetch: loads above may not sink into the compute below.
        __builtin_amdgcn_sched_barrier(0);

        // e / px / py at row o+1, cols g-1..g+4 (i=0..5 ; window j=i..i+2)
        float eN[6], PXN[6], PYNc[4];
        const bool rowv = (o >= -1) && (o < HH - 1);   // wave-uniform
        if (rowv) {
            #pragma unroll
            for (int i = 0; i < 6; ++i) {
                float ex = (I0.w[i] - I0.w[i+2]) + 2.f * (I1.w[i] - I1.w[i+2]) + (C.w[i] - C.w[i+2]);
                float ey = (I0.w[i] - C.w[i]) + 2.f * (I0.w[i+1] - C.w[i+1]) + (I0.w[i+2] - C.w[i+2]);
                float s2 = ex * ex + ey * ey;
                eN[i] = M * __builtin_amdgcn_rcpf(s2 * s2 + M);
                float gux = R2.w[i+2] - R2.w[i];
                float guy = R1.w[i+1] - W.w[i+1];
                float rn  = __builtin_amdgcn_rsqf(gux * gux + guy * guy + EPSF);
                PXN[i] = gux * rn;
                if (i >= 1 && i <= 4) PYNc[i-1] = guy * rn;   // center cols only
            }
            // image-border cols: edges conv input is zero-padded
            if (ezL) { eN[0] = 0.f; PXN[0] = 0.f; }
            if (ezR) { eN[5] = 0.f; PXN[5] = 0.f; }
        } else {
            #pragma unroll
            for (int i = 0; i < 6; ++i) { eN[i] = 0.f; PXN[i] = 0.f; }
            #pragma unroll
            for (int k = 0; k < 4; ++k) PYNc[k] = 0.f;
        }

        if (o >= o0) {   // emit output row o (center cols g..g+3: i=k2+1, j=k2+2)
            float vals[4];
            #pragma unroll
            for (int k2 = 0; k2 < 4; ++k2) {
                const int i = k2 + 1, j = k2 + 2;
                float gex = E2[i+1] - E2[i-1];
                float gey = E1c[k2] - eN[i];
                float xp = R1.w[j+1] - R1.w[j], xn = R1.w[j] - R1.w[j-1];
                float yp = R0[k2] - R1.w[j],    yn = R1.w[j] - R2.w[j];
                float tr = fmaxf(gex, 0.f) * xp + fminf(gex, 0.f) * xn
                         + fmaxf(gey, 0.f) * yp + fminf(gey, 0.f) * yn;
                float gxc = R1.w[j+1] - R1.w[j-1], gyc = R0[k2] - R2.w[j];
                float ncv = __builtin_amdgcn_sqrtf(gxc * gxc + gyc * gyc + EPSF);
                float kap = (PX2[i+1] - PX2[i-1]) + (PY1c[k2] - PYNc[k2]);
                vals[k2] = R1.w[j] + E2[i] * ncv * (kap * dta + dtg) + tr * dtb;
            }
            // non-temporal: don't evict LLC-resident img with write-allocate
            vfloat4 vv = { vals[0], vals[1], vals[2], vals[3] };
            __builtin_nontemporal_store(vv, (vfloat4*)(O + (size_t)o * WW + g));
        }

        // roll
        I0 = I1; I1 = C;
        #pragma unroll
        for (int k2 = 0; k2 < 4; ++k2) {
            R0[k2] = R1.w[k2+2]; E1c[k2] = E2[k2+1];
            PY1c[k2] = PY2c[k2]; PY2c[k2] = PYNc[k2];
        }
        R1 = R2; R2 = W;
        #pragma unroll
        for (int i = 0; i < 6; ++i) { E2[i] = eN[i]; PX2[i] = PXN[i]; }
    }
}

extern "C" void kernel_launch(void* const* d_in, const int* in_sizes, int n_in,
                              void* d_out, int out_size, void* d_ws, size_t ws_size,
                              hipStream_t stream) {
    const float* u   = (const float*)d_in[0];
    const float* img = (const float*)d_in[1];
    const float* pa  = (const float*)d_in[2];
    const float* pb  = (const float*)d_in[3];
    const float* pg  = (const float*)d_in[4];
    float* out = (float*)d_out;
    float* partial = (float*)d_ws;        // 8192 floats, all written unconditionally

    // pass 1: 256 strips x 32 batch = 8192 waves = 2048 blocks (8/CU @40 VGPR)
    max_e4_kernel<<<2048, 256, 0, stream>>>(img, partial);
    // pass 2: 2 panels x 64 strips x 32 batch = 4096 waves = 1024 blocks
    fused_ff<<<1024, 256, 0, stream>>>(u, img, pa, pb, pg, partial, out);
}

// Round 11
// 127.455 us; speedup vs baseline: 1.0013x; 1.0013x over previous
//
#include <hip/hip_runtime.h>

#define HH 512
#define WW 512
#define EPSF 1e-7f
#define DTF 0.05f
#define RS1 4      // rows per wave, pass 1 (128 strips/image -> 4096 waves, 1024 blocks)
#define RSF 4      // output rows per wave, pass 2 (128 strips -> 8192 waves, 2048 blocks)
#define PANW 256   // panel width, pass 2 (4 cols/lane)

// lane-to-lane pull via LDS-pipe permute (pass 1 only)
__device__ __forceinline__ float bperm(int addr, float v) {
    return __int_as_float(__builtin_amdgcn_ds_bpermute(addr, __float_as_int(v)));
}

// ---------------- Pass 1: per-wave strip max of e4 -> partial[] (NO atomics) ----------------
// Round-5 evidence: same-address device atomicMax serializes (~11.5 ns each -> 47 us tail).
// Round-10 evidence: RS1=2 halo amplification regressed; RS1=4 (round 7) is the sweet spot.
struct R10 { float v[10]; };
struct Raw10 { float4 a, b; };

__device__ __forceinline__ void issue_row10(const float* __restrict__ base, int row,
                                            int lane, Raw10& r) {
    if ((unsigned)row < (unsigned)HH) {               // wave-uniform branch
        const float4* p = (const float4*)(base + (size_t)row * WW + 8 * lane);
        r.a = p[0]; r.b = p[1];
    } else {
        r.a = make_float4(0.f, 0.f, 0.f, 0.f);
        r.b = make_float4(0.f, 0.f, 0.f, 0.f);
    }
}

__device__ __forceinline__ void finish_row10(const Raw10& q, int bpu, int bpd,
                                             bool lo, bool hi, R10& r) {
    r.v[1] = q.a.x; r.v[2] = q.a.y; r.v[3] = q.a.z; r.v[4] = q.a.w;
    r.v[5] = q.b.x; r.v[6] = q.b.y; r.v[7] = q.b.z; r.v[8] = q.b.w;
    float l = bperm(bpu, r.v[8]);
    float h = bperm(bpd, r.v[1]);
    r.v[0] = lo ? 0.f : l;
    r.v[9] = hi ? 0.f : h;
}

__global__ __launch_bounds__(256, 4)
void max_e4_kernel(const float* __restrict__ img, float* __restrict__ partial) {
    const int wid  = blockIdx.x * 4 + (threadIdx.x >> 6);
    const int lane = threadIdx.x & 63;
    const int rs = wid & 127;                // 128 strips of RS1 rows
    const int b  = wid >> 7;
    const int i0 = rs * RS1;
    const float* __restrict__ IM = img + (size_t)b * (HH * WW);
    const bool lo = (lane == 0), hi = (lane == 63);
    const int bpu = ((lane + 63) & 63) << 2, bpd = ((lane + 1) & 63) << 2;

    Raw10 rA, rB;
    issue_row10(IM, i0 - 1, lane, rA);
    issue_row10(IM, i0,     lane, rB);
    R10 A, B, C;
    finish_row10(rA, bpu, bpd, lo, hi, A);
    issue_row10(IM, i0 + 1, lane, rA);
    finish_row10(rB, bpu, bpd, lo, hi, B);
    issue_row10(IM, i0 + 2, lane, rB);
    float m = 0.f;
    #pragma unroll
    for (int k = 0; k < RS1; ++k) {          // row i0+k, uses raw row i0+k+1
        if (k & 1) {
            finish_row10(rB, bpu, bpd, lo, hi, C);
            if (k < RS1 - 2) issue_row10(IM, i0 + k + 3, lane, rB);
        } else {
            finish_row10(rA, bpu, bpd, lo, hi, C);
            if (k < RS1 - 2) issue_row10(IM, i0 + k + 3, lane, rA);
        }
        #pragma unroll
        for (int j = 1; j <= 8; ++j) {
            float ex = (A.v[j-1] - A.v[j+1]) + 2.f * (B.v[j-1] - B.v[j+1]) + (C.v[j-1] - C.v[j+1]);
            float ey = (A.v[j-1] - C.v[j-1]) + 2.f * (A.v[j] - C.v[j]) + (A.v[j+1] - C.v[j+1]);
            float s2 = ex * ex + ey * ey;
            m = fmaxf(m, s2 * s2);
        }
        A = B; B = C;
    }
    for (int off = 32; off > 0; off >>= 1)
        m = fmaxf(m, __shfl_down(m, off, 64));
    if (lane == 0) partial[wid] = m;         // 4096 partials, all written every launch
}

// ---------------- Pass 2: bperm-free, 8-wide self-sufficient lane windows ----------------
// Round-7 proven body (124.0 us total). Each lane owns output cols g..g+3 and loads
// cols g-2..g+5 (float2+float4+float2, naturally aligned, same cache lines as
// neighbors). e/px computed at 6 cols g-1..g+4 in-lane: halo values bitwise-identical
// to the neighbor lane's center computation. No ds_bpermute, no lgkm waits.
// ROUND-11 SINGLE VARIABLE: RSF 8->4, grid 1024->2048 (occupancy 4 -> ~5+ blocks/CU;
// round-6 counters: VALUBusy 25%, HBM 16%, Occ 20% -> latency-bound, wants more waves).
struct Raw8 { float2 L; float4 C4; float2 R; };
struct W8 { float w[8]; };   // w[j] = col g-2+j (0 outside image)

__device__ __forceinline__ void issue8(const float* __restrict__ base, int row,
                                       int g, bool okL, bool okR, Raw8& r) {
    if ((unsigned)row < (unsigned)HH) {               // wave-uniform branch
        const float* rp = base + (size_t)row * WW;
        r.L  = *(const float2*)(rp + (okL ? g - 2 : 0));       // clamp: zeroed in finish
        r.C4 = *(const float4*)(rp + g);
        r.R  = *(const float2*)(rp + (okR ? g + 4 : WW - 2));  // clamp: zeroed in finish
    } else {
        r.L  = make_float2(0.f, 0.f);
        r.C4 = make_float4(0.f, 0.f, 0.f, 0.f);
        r.R  = make_float2(0.f, 0.f);
    }
}

__device__ __forceinline__ void finish8(const Raw8& q, bool okL, bool okR, W8& r) {
    r.w[0] = okL ? q.L.x : 0.f;
    r.w[1] = okL ? q.L.y : 0.f;
    r.w[2] = q.C4.x; r.w[3] = q.C4.y; r.w[4] = q.C4.z; r.w[5] = q.C4.w;
    r.w[6] = okR ? q.R.x : 0.f;
    r.w[7] = okR ? q.R.y : 0.f;
}

// (256,2): 256-VGPR cap. Round-1 evidence: never cap at 128 ((256,4)) -> allocator
// collapse + scratch spills. Round-6/7 evidence: this body = 92 VGPR, zero spill.
__global__ __launch_bounds__(256, 2)
void fused_ff(const float* __restrict__ u, const float* __restrict__ img,
              const float* __restrict__ pa, const float* __restrict__ pb,
              const float* __restrict__ pg, const float* __restrict__ partial,
              float* __restrict__ out) {
    // folded reduce_max: every block redundantly reduces the 4096 LLC-hot partials
    __shared__ float sred[4];
    {
        float v = 0.f;
        #pragma unroll
        for (int k = 0; k < 16; ++k)
            v = fmaxf(v, partial[threadIdx.x + 256 * k]);
        for (int off = 32; off > 0; off >>= 1)
            v = fmaxf(v, __shfl_down(v, off, 64));
        if ((threadIdx.x & 63) == 0) sred[threadIdx.x >> 6] = v;
    }
    __syncthreads();
    const float M = fmaxf(fmaxf(sred[0], sred[1]), fmaxf(sred[2], sred[3]));

    const int wid  = blockIdx.x * 4 + (threadIdx.x >> 6);   // [0,8192)
    const int lane = threadIdx.x & 63;
    const int p  = wid & 1;                  // panel
    const int rs = (wid >> 1) & 127;         // 128 strips of RSF rows
    const int b  = wid >> 8;
    const int o0 = rs * RSF;
    const int g  = p * PANW + 4 * lane;      // lane's first output col
    const size_t base = (size_t)b * (HH * WW);
    const float* __restrict__ U  = u + base;
    const float* __restrict__ IM = img + base;
    float* __restrict__ O = out + base;
    const bool okL = (g >= 2);               // cols g-2,g-1 inside image
    const bool okR = (g + 5 < WW);           // cols g+4,g+5 inside image
    const bool ezL = (g == 0);               // e/px col g-1 is conv-pad zero
    const bool ezR = (g + 4 >= WW);          // e/px col g+4 is conv-pad zero

    const float dta = DTF * pa[0];
    const float dtb = 20.f * DTF * pb[0];
    const float dtg = DTF * pg[0];

    // rolling state: img rows o,o+1 (8-wide); u rows o-1(center),o,o+1 ; e/px/py history
    W8 I0 = {}, I1 = {}, R1 = {}, R2 = {};
    float R0[4] = {}, E1c[4] = {}, E2[6] = {}, PX2[6] = {};
    float PY1c[4] = {}, PY2c[4] = {};

    if (o0 >= 2) {   // wave-uniform preload of rows o0-2, o0-1 (issue all, then finish)
        Raw8 qa, qb, qc, qd;
        issue8(IM, o0 - 2, g, okL, okR, qa);
        issue8(U,  o0 - 2, g, okL, okR, qb);
        issue8(IM, o0 - 1, g, okL, okR, qc);
        issue8(U,  o0 - 1, g, okL, okR, qd);
        finish8(qa, okL, okR, I0);
        finish8(qb, okL, okR, R1);
        finish8(qc, okL, okR, I1);
        finish8(qd, okL, okR, R2);
    }

    // depth-2 prefetch ring: slot A = row o0+kk (even kk), slot B (odd kk)
    Raw8 pAi, pAu, pBi, pBu;
    issue8(IM, o0,     g, okL, okR, pAi);
    issue8(U,  o0,     g, okL, okR, pAu);
    issue8(IM, o0 + 1, g, okL, okR, pBi);
    issue8(U,  o0 + 1, g, okL, okR, pBu);

    #pragma unroll
    for (int kk = 0; kk < RSF + 2; ++kk) {
        const int o = o0 - 2 + kk;           // uses raw row o+2 = o0+kk
        W8 C, W;
        if (kk & 1) {
            finish8(pBi, okL, okR, C);
            finish8(pBu, okL, okR, W);
            if (kk < RSF) {                  // compile-time (kk is unrolled)
                issue8(IM, o0 + kk + 2, g, okL, okR, pBi);
                issue8(U,  o0 + kk + 2, g, okL, okR, pBu);
            }
        } else {
            finish8(pAi, okL, okR, C);
            finish8(pAu, okL, okR, W);
            if (kk < RSF) {
                issue8(IM, o0 + kk + 2, g, okL, okR, pAi);
                issue8(U,  o0 + kk + 2, g, okL, okR, pAu);
            }
        }

        // e / px / py at row o+1, cols g-1..g+4 (i=0..5 ; window j=i..i+2)
        float eN[6], PXN[6], PYNc[4];
        const bool rowv = (o >= -1) && (o < HH - 1);   // wave-uniform
        if (rowv) {
            #pragma unroll
            for (int i = 0; i < 6; ++i) {
                float ex = (I0.w[i] - I0.w[i+2]) + 2.f * (I1.w[i] - I1.w[i+2]) + (C.w[i] - C.w[i+2]);
                float ey = (I0.w[i] - C.w[i]) + 2.f * (I0.w[i+1] - C.w[i+1]) + (I0.w[i+2] - C.w[i+2]);
                float s2 = ex * ex + ey * ey;
                eN[i] = M * __builtin_amdgcn_rcpf(s2 * s2 + M);
                float gux = R2.w[i+2] - R2.w[i];
                float guy = R1.w[i+1] - W.w[i+1];
                float rn  = __builtin_amdgcn_rsqf(gux * gux + guy * guy + EPSF);
                PXN[i] = gux * rn;
                if (i >= 1 && i <= 4) PYNc[i-1] = guy * rn;   // center cols only
            }
            // image-border cols: edges conv input is zero-padded
            if (ezL) { eN[0] = 0.f; PXN[0] = 0.f; }
            if (ezR) { eN[5] = 0.f; PXN[5] = 0.f; }
        } else {
            #pragma unroll
            for (int i = 0; i < 6; ++i) { eN[i] = 0.f; PXN[i] = 0.f; }
            #pragma unroll
            for (int k = 0; k < 4; ++k) PYNc[k] = 0.f;
        }

        if (o >= o0) {   // emit output row o (center cols g..g+3: i=k2+1, j=k2+2)
            float vals[4];
            #pragma unroll
            for (int k2 = 0; k2 < 4; ++k2) {
                const int i = k2 + 1, j = k2 + 2;
                float gex = E2[i+1] - E2[i-1];
                float gey = E1c[k2] - eN[i];
                float xp = R1.w[j+1] - R1.w[j], xn = R1.w[j] - R1.w[j-1];
                float yp = R0[k2] - R1.w[j],    yn = R1.w[j] - R2.w[j];
                float tr = fmaxf(gex, 0.f) * xp + fminf(gex, 0.f) * xn
                         + fmaxf(gey, 0.f) * yp + fminf(gey, 0.f) * yn;
                float gxc = R1.w[j+1] - R1.w[j-1], gyc = R0[k2] - R2.w[j];
                float ncv = __builtin_amdgcn_sqrtf(gxc * gxc + gyc * gyc + EPSF);
                float kap = (PX2[i+1] - PX2[i-1]) + (PY1c[k2] - PYNc[k2]);
                vals[k2] = R1.w[j] + E2[i] * ncv * (kap * dta + dtg) + tr * dtb;
            }
            *(float4*)(O + (size_t)o * WW + g) =
                make_float4(vals[0], vals[1], vals[2], vals[3]);
        }

        // roll
        I0 = I1; I1 = C;
        #pragma unroll
        for (int k2 = 0; k2 < 4; ++k2) {
            R0[k2] = R1.w[k2+2]; E1c[k2] = E2[k2+1];
            PY1c[k2] = PY2c[k2]; PY2c[k2] = PYNc[k2];
        }
        R1 = R2; R2 = W;
        #pragma unroll
        for (int i = 0; i < 6; ++i) { E2[i] = eN[i]; PX2[i] = PXN[i]; }
    }
}

extern "C" void kernel_launch(void* const* d_in, const int* in_sizes, int n_in,
                              void* d_out, int out_size, void* d_ws, size_t ws_size,
                              hipStream_t stream) {
    const float* u   = (const float*)d_in[0];
    const float* img = (const float*)d_in[1];
    const float* pa  = (const float*)d_in[2];
    const float* pb  = (const float*)d_in[3];
    const float* pg  = (const float*)d_in[4];
    float* out = (float*)d_out;
    float* partial = (float*)d_ws;        // 4096 floats, all written unconditionally

    // pass 1: 128 strips x 32 batch = 4096 waves = 1024 blocks (4/CU, round-7 proven)
    max_e4_kernel<<<1024, 256, 0, stream>>>(img, partial);
    // pass 2: 2 panels x 128 strips x 32 batch = 8192 waves = 2048 blocks
    fused_ff<<<2048, 256, 0, stream>>>(u, img, pa, pb, pg, partial, out);
}

// Round 12
// 125.423 us; speedup vs baseline: 1.0175x; 1.0162x over previous
//
#include <hip/hip_runtime.h>

#define HH 512
#define WW 512
#define EPSF 1e-7f
#define DTF 0.05f
#define RS1 4      // rows per wave, pass 1 (128 strips/image -> 4096 waves)
#define RSF 8      // output rows per wave, pass 2
#define PANW 256   // panel width, pass 2 (4 cols/lane)

// lane-to-lane pull via LDS-pipe permute (pass 1 only)
__device__ __forceinline__ float bperm(int addr, float v) {
    return __int_as_float(__builtin_amdgcn_ds_bpermute(addr, __float_as_int(v)));
}

// ---------------- Pass 1: per-wave strip max of e4 -> partial[] (NO atomics) ----------------
// Round-5 evidence: same-address device atomicMax serializes (~11.5 ns each -> 47 us tail).
// Round-10 evidence: RS1=2 halo amplification regressed; RS1=4 is the sweet spot.
struct R10 { float v[10]; };
struct Raw10 { float4 a, b; };

__device__ __forceinline__ void issue_row10(const float* __restrict__ base, int row,
                                            int lane, Raw10& r) {
    if ((unsigned)row < (unsigned)HH) {               // wave-uniform branch
        const float4* p = (const float4*)(base + (size_t)row * WW + 8 * lane);
        r.a = p[0]; r.b = p[1];
    } else {
        r.a = make_float4(0.f, 0.f, 0.f, 0.f);
        r.b = make_float4(0.f, 0.f, 0.f, 0.f);
    }
}

__device__ __forceinline__ void finish_row10(const Raw10& q, int bpu, int bpd,
                                             bool lo, bool hi, R10& r) {
    r.v[1] = q.a.x; r.v[2] = q.a.y; r.v[3] = q.a.z; r.v[4] = q.a.w;
    r.v[5] = q.b.x; r.v[6] = q.b.y; r.v[7] = q.b.z; r.v[8] = q.b.w;
    float l = bperm(bpu, r.v[8]);
    float h = bperm(bpd, r.v[1]);
    r.v[0] = lo ? 0.f : l;
    r.v[9] = hi ? 0.f : h;
}

__global__ __launch_bounds__(256, 4)
void max_e4_kernel(const float* __restrict__ img, float* __restrict__ partial) {
    const int wid  = blockIdx.x * 4 + (threadIdx.x >> 6);
    const int lane = threadIdx.x & 63;
    const int rs = wid & 127;                // 128 strips of RS1 rows
    const int b  = wid >> 7;
    const int i0 = rs * RS1;
    const float* __restrict__ IM = img + (size_t)b * (HH * WW);
    const bool lo = (lane == 0), hi = (lane == 63);
    const int bpu = ((lane + 63) & 63) << 2, bpd = ((lane + 1) & 63) << 2;

    Raw10 rA, rB;
    issue_row10(IM, i0 - 1, lane, rA);
    issue_row10(IM, i0,     lane, rB);
    R10 A, B, C;
    finish_row10(rA, bpu, bpd, lo, hi, A);
    issue_row10(IM, i0 + 1, lane, rA);
    finish_row10(rB, bpu, bpd, lo, hi, B);
    issue_row10(IM, i0 + 2, lane, rB);
    float m = 0.f;
    #pragma unroll
    for (int k = 0; k < RS1; ++k) {          // row i0+k, uses raw row i0+k+1
        if (k & 1) {
            finish_row10(rB, bpu, bpd, lo, hi, C);
            if (k < RS1 - 2) issue_row10(IM, i0 + k + 3, lane, rB);
        } else {
            finish_row10(rA, bpu, bpd, lo, hi, C);
            if (k < RS1 - 2) issue_row10(IM, i0 + k + 3, lane, rA);
        }
        #pragma unroll
        for (int j = 1; j <= 8; ++j) {
            float ex = (A.v[j-1] - A.v[j+1]) + 2.f * (B.v[j-1] - B.v[j+1]) + (C.v[j-1] - C.v[j+1]);
            float ey = (A.v[j-1] - C.v[j-1]) + 2.f * (A.v[j] - C.v[j]) + (A.v[j+1] - C.v[j+1]);
            float s2 = ex * ex + ey * ey;
            m = fmaxf(m, s2 * s2);
        }
        A = B; B = C;
    }
    for (int off = 32; off > 0; off >>= 1)
        m = fmaxf(m, __shfl_down(m, off, 64));
    if (lane == 0) partial[wid] = m;         // 4096 partials, all written every launch
}

// ---------------- Pass 2: bperm-free, 8-wide self-sufficient lane windows ----------------
// Round-7 proven body (session best: 124.0 us total). Each lane owns output cols
// g..g+3 and loads cols g-2..g+5 (float2+float4+float2, naturally aligned, same
// cache lines as neighbors -> no extra HBM traffic). e/px computed at 6 cols
// g-1..g+4 in-lane: halo values bitwise-identical to the neighbor lane's center
// computation. No ds_bpermute, no lgkm waits on the critical path.
struct Raw8 { float2 L; float4 C4; float2 R; };
struct W8 { float w[8]; };   // w[j] = col g-2+j (0 outside image)

__device__ __forceinline__ void issue8(const float* __restrict__ base, int row,
                                       int g, bool okL, bool okR, Raw8& r) {
    if ((unsigned)row < (unsigned)HH) {               // wave-uniform branch
        const float* rp = base + (size_t)row * WW;
        r.L  = *(const float2*)(rp + (okL ? g - 2 : 0));       // clamp: zeroed in finish
        r.C4 = *(const float4*)(rp + g);
        r.R  = *(const float2*)(rp + (okR ? g + 4 : WW - 2));  // clamp: zeroed in finish
    } else {
        r.L  = make_float2(0.f, 0.f);
        r.C4 = make_float4(0.f, 0.f, 0.f, 0.f);
        r.R  = make_float2(0.f, 0.f);
    }
}

__device__ __forceinline__ void finish8(const Raw8& q, bool okL, bool okR, W8& r) {
    r.w[0] = okL ? q.L.x : 0.f;
    r.w[1] = okL ? q.L.y : 0.f;
    r.w[2] = q.C4.x; r.w[3] = q.C4.y; r.w[4] = q.C4.z; r.w[5] = q.C4.w;
    r.w[6] = okR ? q.R.x : 0.f;
    r.w[7] = okR ? q.R.y : 0.f;
}

// (256,2): 256-VGPR cap. Round-1 evidence: never cap at 128 ((256,4)) -> allocator
// collapse + scratch spills. Round-6/7 evidence: this body = ~92-96 VGPR, zero spill.
__global__ __launch_bounds__(256, 2)
void fused_ff(const float* __restrict__ u, const float* __restrict__ img,
              const float* __restrict__ pa, const float* __restrict__ pb,
              const float* __restrict__ pg, const float* __restrict__ partial,
              float* __restrict__ out) {
    // folded reduce_max: every block redundantly reduces the 4096 LLC-hot partials
    __shared__ float sred[4];
    {
        float v = 0.f;
        #pragma unroll
        for (int k = 0; k < 16; ++k)
            v = fmaxf(v, partial[threadIdx.x + 256 * k]);
        for (int off = 32; off > 0; off >>= 1)
            v = fmaxf(v, __shfl_down(v, off, 64));
        if ((threadIdx.x & 63) == 0) sred[threadIdx.x >> 6] = v;
    }
    __syncthreads();
    const float M = fmaxf(fmaxf(sred[0], sred[1]), fmaxf(sred[2], sred[3]));

    const int wid  = blockIdx.x * 4 + (threadIdx.x >> 6);   // [0,4096)
    const int lane = threadIdx.x & 63;
    const int p  = wid & 1;                  // panel
    const int rs = (wid >> 1) & 63;          // 64 strips of RSF rows
    const int b  = wid >> 7;
    const int o0 = rs * RSF;
    const int g  = p * PANW + 4 * lane;      // lane's first output col
    const size_t base = (size_t)b * (HH * WW);
    const float* __restrict__ U  = u + base;
    const float* __restrict__ IM = img + base;
    float* __restrict__ O = out + base;
    const bool okL = (g >= 2);               // cols g-2,g-1 inside image
    const bool okR = (g + 5 < WW);           // cols g+4,g+5 inside image
    const bool ezL = (g == 0);               // e/px col g-1 is conv-pad zero
    const bool ezR = (g + 4 >= WW);          // e/px col g+4 is conv-pad zero

    const float dta = DTF * pa[0];
    const float dtb = 20.f * DTF * pb[0];
    const float dtg = DTF * pg[0];

    // rolling state: img rows o,o+1 (8-wide); u rows o-1(center),o,o+1 ; e/px/py history
    W8 I0 = {}, I1 = {}, R1 = {}, R2 = {};
    float R0[4] = {}, E1c[4] = {}, E2[6] = {}, PX2[6] = {};
    float PY1c[4] = {}, PY2c[4] = {};

    if (o0 >= 2) {   // wave-uniform preload of rows o0-2, o0-1 (issue all, then finish)
        Raw8 qa, qb, qc, qd;
        issue8(IM, o0 - 2, g, okL, okR, qa);
        issue8(U,  o0 - 2, g, okL, okR, qb);
        issue8(IM, o0 - 1, g, okL, okR, qc);
        issue8(U,  o0 - 1, g, okL, okR, qd);
        finish8(qa, okL, okR, I0);
        finish8(qb, okL, okR, R1);
        finish8(qc, okL, okR, I1);
        finish8(qd, okL, okR, R2);
    }

    // depth-2 prefetch ring: slot A = row o0+kk (even kk), slot B (odd kk)
    Raw8 pAi, pAu, pBi, pBu;
    issue8(IM, o0,     g, okL, okR, pAi);
    issue8(U,  o0,     g, okL, okR, pAu);
    issue8(IM, o0 + 1, g, okL, okR, pBi);
    issue8(U,  o0 + 1, g, okL, okR, pBu);

    #pragma unroll
    for (int kk = 0; kk < RSF + 2; ++kk) {
        const int o = o0 - 2 + kk;           // uses raw row o+2 = o0+kk
        W8 C, W;
        if (kk & 1) {
            finish8(pBi, okL, okR, C);
            finish8(pBu, okL, okR, W);
            if (kk < RSF) {                  // compile-time (kk is unrolled)
                issue8(IM, o0 + kk + 2, g, okL, okR, pBi);
                issue8(U,  o0 + kk + 2, g, okL, okR, pBu);
            }
        } else {
            finish8(pAi, okL, okR, C);
            finish8(pAu, okL, okR, W);
            if (kk < RSF) {
                issue8(IM, o0 + kk + 2, g, okL, okR, pAi);
                issue8(U,  o0 + kk + 2, g, okL, okR, pAu);
            }
        }

        // e / px / py at row o+1, cols g-1..g+4 (i=0..5 ; window j=i..i+2)
        float eN[6], PXN[6], PYNc[4];
        const bool rowv = (o >= -1) && (o < HH - 1);   // wave-uniform
        if (rowv) {
            #pragma unroll
            for (int i = 0; i < 6; ++i) {
                float ex = (I0.w[i] - I0.w[i+2]) + 2.f * (I1.w[i] - I1.w[i+2]) + (C.w[i] - C.w[i+2]);
                float ey = (I0.w[i] - C.w[i]) + 2.f * (I0.w[i+1] - C.w[i+1]) + (I0.w[i+2] - C.w[i+2]);
                float s2 = ex * ex + ey * ey;
                eN[i] = M * __builtin_amdgcn_rcpf(s2 * s2 + M);
                float gux = R2.w[i+2] - R2.w[i];
                float guy = R1.w[i+1] - W.w[i+1];
                float rn  = __builtin_amdgcn_rsqf(gux * gux + guy * guy + EPSF);
                PXN[i] = gux * rn;
                if (i >= 1 && i <= 4) PYNc[i-1] = guy * rn;   // center cols only
            }
            // image-border cols: edges conv input is zero-padded
            if (ezL) { eN[0] = 0.f; PXN[0] = 0.f; }
            if (ezR) { eN[5] = 0.f; PXN[5] = 0.f; }
        } else {
            #pragma unroll
            for (int i = 0; i < 6; ++i) { eN[i] = 0.f; PXN[i] = 0.f; }
            #pragma unroll
            for (int k = 0; k < 4; ++k) PYNc[k] = 0.f;
        }

        if (o >= o0) {   // emit output row o (center cols g..g+3: i=k2+1, j=k2+2)
            float vals[4];
            #pragma unroll
            for (int k2 = 0; k2 < 4; ++k2) {
                const int i = k2 + 1, j = k2 + 2;
                float gex = E2[i+1] - E2[i-1];
                float gey = E1c[k2] - eN[i];
                float xp = R1.w[j+1] - R1.w[j], xn = R1.w[j] - R1.w[j-1];
                float yp = R0[k2] - R1.w[j],    yn = R1.w[j] - R2.w[j];
                float tr = fmaxf(gex, 0.f) * xp + fminf(gex, 0.f) * xn
                         + fmaxf(gey, 0.f) * yp + fminf(gey, 0.f) * yn;
                float gxc = R1.w[j+1] - R1.w[j-1], gyc = R0[k2] - R2.w[j];
                float ncv = __builtin_amdgcn_sqrtf(gxc * gxc + gyc * gyc + EPSF);
                float kap = (PX2[i+1] - PX2[i-1]) + (PY1c[k2] - PYNc[k2]);
                vals[k2] = R1.w[j] + E2[i] * ncv * (kap * dta + dtg) + tr * dtb;
            }
            *(float4*)(O + (size_t)o * WW + g) =
                make_float4(vals[0], vals[1], vals[2], vals[3]);
        }

        // roll
        I0 = I1; I1 = C;
        #pragma unroll
        for (int k2 = 0; k2 < 4; ++k2) {
            R0[k2] = R1.w[k2+2]; E1c[k2] = E2[k2+1];
            PY1c[k2] = PY2c[k2]; PY2c[k2] = PYNc[k2];
        }
        R1 = R2; R2 = W;
        #pragma unroll
        for (int i = 0; i < 6; ++i) { E2[i] = eN[i]; PX2[i] = PXN[i]; }
    }
}

extern "C" void kernel_launch(void* const* d_in, const int* in_sizes, int n_in,
                              void* d_out, int out_size, void* d_ws, size_t ws_size,
                              hipStream_t stream) {
    const float* u   = (const float*)d_in[0];
    const float* img = (const float*)d_in[1];
    const float* pa  = (const float*)d_in[2];
    const float* pb  = (const float*)d_in[3];
    const float* pg  = (const float*)d_in[4];
    float* out = (float*)d_out;
    float* partial = (float*)d_ws;        // 4096 floats, all written unconditionally

    // pass 1: 128 strips x 32 batch = 4096 waves = 1024 blocks (4/CU); plain stores
    max_e4_kernel<<<1024, 256, 0, stream>>>(img, partial);
    // pass 2: 2 panels x 64 strips x 32 batch = 4096 waves = 1024 blocks
    fused_ff<<<1024, 256, 0, stream>>>(u, img, pa, pb, pg, partial, out);
}